// Round 1
// baseline (630.045 us; speedup 1.0000x reference)
//
#include <hip/hip_runtime.h>
#include <math.h>

// ---------------- constants ----------------
// Stage1: N=4096 -> np=128, r=0.02, ns=32, layers (9->32), (32->64)
// Stage2: N=128  -> np=64,  r=0.04, ns=32, layers (67->128), (128->128)
// Stage3: N=64   -> np=32,  r=0.08, ns=16, layers (131->256), (256->256)
//
// ws layout (floats):
//   wT (transposed, padded, BN-scale folded): [0, 126848)
//     L0 off 0     (12x32)    L1 off 384   (32x64)
//     L2 off 2432  (68x128)   L3 off 11136 (128x128)
//     L4 off 27520 (132x256)  L5 off 61312 (256x256)
//   bias: [126848, 127712)  offs 0,32,96,224,352,608
//   xyz1 131072 (64*128*3)  xyz2 155648 (64*64*3)  xyz3 167936 (64*32*3)
//   f1   174080 (64*128*64) f2 698368 (64*64*128)

__global__ void prep_layer(const float* __restrict__ w, const float* __restrict__ g,
                           const float* __restrict__ be, const float* __restrict__ rm,
                           const float* __restrict__ rv, float* __restrict__ wT,
                           float* __restrict__ bias, int cin, int cinp, int cout) {
  int i = blockIdx.x * blockDim.x + threadIdx.x;
  int tot = cout * cinp;
  if (i < tot) {
    int c = i / cout, o = i - c * cout;
    float sc = g[o] / sqrtf(rv[o] + 1e-5f);
    wT[i] = (c < cin) ? w[o * cin + c] * sc : 0.f;
  }
  if (i < cout) {
    float sc = g[i] / sqrtf(rv[i] + 1e-5f);
    bias[i] = be[i] - rm[i] * sc;
  }
}

// exact (non-contracted) squared distance, matching numpy op order
__device__ __forceinline__ float dist2_exact(float px, float py, float pz,
                                             float cx, float cy, float cz) {
  float dx = px - cx, dy = py - cy, dz = pz - cz;
  return __fadd_rn(__fadd_rn(__fmul_rn(dx, dx), __fmul_rn(dy, dy)), __fmul_rn(dz, dz));
}

// ---------------- FPS stage 1: N=4096, npoint=128 ----------------
__global__ __launch_bounds__(256) void fps1_kernel(const float* __restrict__ pc,
                                                   float* __restrict__ newxyz) {
  int b = blockIdx.x;
  const float* xb = pc + (size_t)b * 4096 * 3;
  float* out = newxyz + (size_t)b * 128 * 3;
  __shared__ float s_pts[4096 * 3];
  __shared__ float s_val[2][4];
  __shared__ int s_idx[2][4];
  int t = threadIdx.x;
  for (int e = t; e < 4096 * 3; e += 256) s_pts[e] = xb[e];
  __syncthreads();
  float px[16], py[16], pz[16], dist[16];
  for (int k = 0; k < 16; ++k) {
    int i = k * 256 + t;
    px[k] = s_pts[i * 3]; py[k] = s_pts[i * 3 + 1]; pz[k] = s_pts[i * 3 + 2];
    dist[k] = 1e10f;
  }
  float cx = s_pts[0], cy = s_pts[1], cz = s_pts[2];
  if (t == 0) { out[0] = cx; out[1] = cy; out[2] = cz; }
  int lane = t & 63, wv = t >> 6;
  for (int it = 1; it < 128; ++it) {
    float bv = -1.f; int bi = 0;
    for (int k = 0; k < 16; ++k) {
      float d = dist2_exact(px[k], py[k], pz[k], cx, cy, cz);
      float nd = fminf(dist[k], d);
      dist[k] = nd;
      if (nd > bv) { bv = nd; bi = k * 256 + t; }  // ascending idx -> strict > keeps first
    }
    for (int off = 32; off >= 1; off >>= 1) {
      float ov = __shfl_down(bv, (unsigned)off, 64);
      int oi = __shfl_down(bi, (unsigned)off, 64);
      if (ov > bv || (ov == bv && oi < bi)) { bv = ov; bi = oi; }
    }
    int pb = it & 1;
    if (lane == 0) { s_val[pb][wv] = bv; s_idx[pb][wv] = bi; }
    __syncthreads();
    float v0 = s_val[pb][0]; int i0 = s_idx[pb][0];
    for (int w = 1; w < 4; ++w) {
      float v = s_val[pb][w]; int ii = s_idx[pb][w];
      if (v > v0 || (v == v0 && ii < i0)) { v0 = v; i0 = ii; }
    }
    cx = s_pts[i0 * 3]; cy = s_pts[i0 * 3 + 1]; cz = s_pts[i0 * 3 + 2];
    if (t == 0) { out[it * 3] = cx; out[it * 3 + 1] = cy; out[it * 3 + 2] = cz; }
  }
}

// ---------------- FPS stage 2: N=128, npoint=64, one wave ----------------
__global__ __launch_bounds__(64) void fps2_kernel(const float* __restrict__ xyz1,
                                                  float* __restrict__ out_xyz) {
  int b = blockIdx.x;
  const float* xb = xyz1 + (size_t)b * 128 * 3;
  float* out = out_xyz + (size_t)b * 64 * 3;
  int t = threadIdx.x;
  float px[2], py[2], pz[2], dist[2];
  for (int k = 0; k < 2; ++k) {
    int i = k * 64 + t;
    px[k] = xb[i * 3]; py[k] = xb[i * 3 + 1]; pz[k] = xb[i * 3 + 2];
    dist[k] = 1e10f;
  }
  float cx = __shfl(px[0], 0, 64), cy = __shfl(py[0], 0, 64), cz = __shfl(pz[0], 0, 64);
  if (t == 0) { out[0] = cx; out[1] = cy; out[2] = cz; }
  for (int it = 1; it < 64; ++it) {
    float bv = -1.f; int bi = 0;
    for (int k = 0; k < 2; ++k) {
      float d = dist2_exact(px[k], py[k], pz[k], cx, cy, cz);
      dist[k] = fminf(dist[k], d);
      if (dist[k] > bv) { bv = dist[k]; bi = k * 64 + t; }
    }
    for (int off = 32; off >= 1; off >>= 1) {
      float ov = __shfl_down(bv, (unsigned)off, 64);
      int oi = __shfl_down(bi, (unsigned)off, 64);
      if (ov > bv || (ov == bv && oi < bi)) { bv = ov; bi = oi; }
    }
    int sel = __shfl(bi, 0, 64);
    int sl = sel & 63, sk = sel >> 6;
    float qx = sk ? px[1] : px[0], qy = sk ? py[1] : py[0], qz = sk ? pz[1] : pz[0];
    cx = __shfl(qx, sl, 64); cy = __shfl(qy, sl, 64); cz = __shfl(qz, sl, 64);
    if (t == 0) { out[it * 3] = cx; out[it * 3 + 1] = cy; out[it * 3 + 2] = cz; }
  }
}

// ---------------- FPS stage 3: N=64, npoint=32, one wave ----------------
__global__ __launch_bounds__(64) void fps3_kernel(const float* __restrict__ xyz2,
                                                  float* __restrict__ out_xyz) {
  int b = blockIdx.x;
  const float* xb = xyz2 + (size_t)b * 64 * 3;
  float* out = out_xyz + (size_t)b * 32 * 3;
  int t = threadIdx.x;
  float px = xb[t * 3], py = xb[t * 3 + 1], pz = xb[t * 3 + 2];
  float dist = 1e10f;
  float cx = __shfl(px, 0, 64), cy = __shfl(py, 0, 64), cz = __shfl(pz, 0, 64);
  if (t == 0) { out[0] = cx; out[1] = cy; out[2] = cz; }
  for (int it = 1; it < 32; ++it) {
    float d = dist2_exact(px, py, pz, cx, cy, cz);
    dist = fminf(dist, d);
    float bv = dist; int bi = t;
    for (int off = 32; off >= 1; off >>= 1) {
      float ov = __shfl_down(bv, (unsigned)off, 64);
      int oi = __shfl_down(bi, (unsigned)off, 64);
      if (ov > bv || (ov == bv && oi < bi)) { bv = ov; bi = oi; }
    }
    int sel = __shfl(bi, 0, 64);
    cx = __shfl(px, sel, 64); cy = __shfl(py, sel, 64); cz = __shfl(pz, sel, 64);
    if (t == 0) { out[it * 3] = cx; out[it * 3 + 1] = cy; out[it * 3 + 2] = cz; }
  }
}

// ---------------- ball query (single wave, lanes 0..63) ----------------
// first `nsample` in-radius indices in ascending order -> list (LDS)
__device__ __forceinline__ int ball_query_wave(const float* __restrict__ xb, int N,
                                               float cx, float cy, float cz, float r2,
                                               int nsample, int* list, int lane) {
  int cnt = 0;
  for (int base = 0; base < N && cnt < nsample; base += 64) {
    int i = base + lane;
    float d2 = dist2_exact(xb[i * 3], xb[i * 3 + 1], xb[i * 3 + 2], cx, cy, cz);
    bool in = d2 < r2;
    unsigned long long m = __ballot(in);
    if (in) {
      int pos = cnt + __popcll(m & ((1ull << lane) - 1ull));
      if (pos < nsample) list[pos] = i;
    }
    cnt += __popcll(m);
  }
  return cnt;
}

// ---------------- group+MLP stage 1: one wave per group ----------------
__global__ __launch_bounds__(64) void group1_kernel(const float* __restrict__ pc,
    const float* __restrict__ newxyz1, const float* __restrict__ wbuf,
    const float* __restrict__ bbuf, float* __restrict__ f1) {
  int s = blockIdx.x, b = blockIdx.y;
  const float* xb = pc + (size_t)b * 4096 * 3;
  const float* ctr = newxyz1 + ((size_t)b * 128 + s) * 3;
  __shared__ int list[32];
  __shared__ float xld[32][12];
  __shared__ float h1[32][32];
  int t = threadIdx.x;
  float cx = ctr[0], cy = ctr[1], cz = ctr[2];
  int cnt = ball_query_wave(xb, 4096, cx, cy, cz, 4.0e-4f, 32, list, t);
  __syncthreads();
  if (t < 32 && t >= cnt) list[t] = (cnt > 0) ? list[0] : 0;
  __syncthreads();
  if (t < 32) {
    int i = list[t];
    float px = xb[i * 3], py = xb[i * 3 + 1], pz = xb[i * 3 + 2];
    xld[t][0] = px - cx; xld[t][1] = py - cy; xld[t][2] = pz - cz;
    xld[t][3] = px; xld[t][4] = py; xld[t][5] = pz;
    xld[t][6] = px; xld[t][7] = py; xld[t][8] = pz;
    xld[t][9] = 0.f; xld[t][10] = 0.f; xld[t][11] = 0.f;
  }
  __syncthreads();
  // layer0: cin 12(pad), cout 32. thread: o=t&31, j in [(t>>5)*16, +16)
  {
    const float* wT = wbuf;  // [12][32]
    int o = t & 31, jb = (t >> 5) * 16;
    float wv[12];
    for (int c = 0; c < 12; ++c) wv[c] = wT[c * 32 + o];
    float bias = bbuf[o];
    for (int jj = 0; jj < 16; ++jj) {
      int j = jb + jj;
      float a = bias;
      for (int c = 0; c < 12; ++c) a = fmaf(wv[c], xld[j][c], a);
      h1[j][o] = fmaxf(a, 0.f);
    }
  }
  __syncthreads();
  // layer1: cin 32, cout 64. thread: o=t, all 32 j, fused max
  {
    const float* wT = wbuf + 384;  // [32][64]
    float bias = bbuf[32 + t];
    float wv[32];
    for (int c = 0; c < 32; ++c) wv[c] = wT[c * 64 + t];
    float mx = -1e30f;
    for (int j = 0; j < 32; ++j) {
      float a = bias;
      for (int c4 = 0; c4 < 8; ++c4) {
        float4 x4 = *reinterpret_cast<const float4*>(&h1[j][c4 * 4]);
        a = fmaf(wv[c4 * 4], x4.x, fmaf(wv[c4 * 4 + 1], x4.y,
            fmaf(wv[c4 * 4 + 2], x4.z, fmaf(wv[c4 * 4 + 3], x4.w, a))));
      }
      mx = fmaxf(mx, fmaxf(a, 0.f));
    }
    f1[((size_t)b * 128 + s) * 64 + t] = mx;
  }
}

// ---------------- group+MLP stage 2 ----------------
__global__ __launch_bounds__(256) void group2_kernel(const float* __restrict__ xyz1,
    const float* __restrict__ newxyz2, const float* __restrict__ f1,
    const float* __restrict__ wT, const float* __restrict__ bb, float* __restrict__ f2) {
  int s = blockIdx.x, b = blockIdx.y;
  const float* xb = xyz1 + (size_t)b * 128 * 3;
  const float* ctr = newxyz2 + ((size_t)b * 64 + s) * 3;
  __shared__ int list[32];
  __shared__ int s_cnt;
  __shared__ float xld[32][68];
  __shared__ float h1[32][128];
  __shared__ float pmax[256];
  int t = threadIdx.x;
  float cx = ctr[0], cy = ctr[1], cz = ctr[2];
  if (t < 64) {
    int c_ = ball_query_wave(xb, 128, cx, cy, cz, 1.6e-3f, 32, list, t);
    if (t == 0) s_cnt = c_;
  }
  __syncthreads();
  int cnt = s_cnt;
  if (t < 32 && t >= cnt) list[t] = (cnt > 0) ? list[0] : 0;
  __syncthreads();
  for (int e = t; e < 32 * 68; e += 256) {
    int j = e / 68, c = e - j * 68;
    int i = list[j];
    float v;
    if (c < 3) v = xb[i * 3 + c] - (c == 0 ? cx : (c == 1 ? cy : cz));
    else if (c < 67) v = f1[((size_t)b * 128 + i) * 64 + (c - 3)];
    else v = 0.f;
    xld[j][c] = v;
  }
  __syncthreads();
  int o = t & 127, jb = (t >> 7) * 16;
  float acc[16];
  // layer2: cin 68(pad), cout 128
  {
    float bias = bb[o];
    for (int jj = 0; jj < 16; ++jj) acc[jj] = bias;
    for (int c4 = 0; c4 < 17; ++c4) {
      int c = c4 * 4;
      float w0 = wT[(c + 0) * 128 + o], w1 = wT[(c + 1) * 128 + o];
      float w2 = wT[(c + 2) * 128 + o], w3 = wT[(c + 3) * 128 + o];
      for (int jj = 0; jj < 16; ++jj) {
        float4 x4 = *reinterpret_cast<const float4*>(&xld[jb + jj][c]);
        acc[jj] = fmaf(w0, x4.x, fmaf(w1, x4.y, fmaf(w2, x4.z, fmaf(w3, x4.w, acc[jj]))));
      }
    }
    for (int jj = 0; jj < 16; ++jj) h1[jb + jj][o] = fmaxf(acc[jj], 0.f);
  }
  __syncthreads();
  // layer3: cin 128, cout 128, fused max over 16 local j then combine halves
  {
    const float* wT3 = wT + 8704;
    float bias = bb[128 + o];
    for (int jj = 0; jj < 16; ++jj) acc[jj] = bias;
    for (int c4 = 0; c4 < 32; ++c4) {
      int c = c4 * 4;
      float w0 = wT3[(c + 0) * 128 + o], w1 = wT3[(c + 1) * 128 + o];
      float w2 = wT3[(c + 2) * 128 + o], w3 = wT3[(c + 3) * 128 + o];
      for (int jj = 0; jj < 16; ++jj) {
        float4 x4 = *reinterpret_cast<const float4*>(&h1[jb + jj][c]);
        acc[jj] = fmaf(w0, x4.x, fmaf(w1, x4.y, fmaf(w2, x4.z, fmaf(w3, x4.w, acc[jj]))));
      }
    }
    float mx = -1e30f;
    for (int jj = 0; jj < 16; ++jj) mx = fmaxf(mx, fmaxf(acc[jj], 0.f));
    pmax[t] = mx;
  }
  __syncthreads();
  if (t < 128) f2[((size_t)b * 64 + s) * 128 + t] = fmaxf(pmax[t], pmax[t + 128]);
}

// ---------------- group+MLP stage 3 ----------------
__global__ __launch_bounds__(256) void group3_kernel(const float* __restrict__ xyz2,
    const float* __restrict__ newxyz3, const float* __restrict__ f2,
    const float* __restrict__ wT4, const float* __restrict__ bb4, float* __restrict__ out) {
  int s = blockIdx.x, b = blockIdx.y;  // s<32
  const float* xb = xyz2 + (size_t)b * 64 * 3;
  const float* ctr = newxyz3 + ((size_t)b * 32 + s) * 3;
  __shared__ int list[16];
  __shared__ int s_cnt;
  __shared__ float xld[16][132];
  __shared__ float h1[16][256];
  int t = threadIdx.x;
  float cx = ctr[0], cy = ctr[1], cz = ctr[2];
  if (t < 64) {
    int c_ = ball_query_wave(xb, 64, cx, cy, cz, 6.4e-3f, 16, list, t);
    if (t == 0) s_cnt = c_;
  }
  __syncthreads();
  int cnt = s_cnt;
  if (t < 16 && t >= cnt) list[t] = (cnt > 0) ? list[0] : 0;
  __syncthreads();
  for (int e = t; e < 16 * 132; e += 256) {
    int j = e / 132, c = e - j * 132;
    int i = list[j];
    float v;
    if (c < 3) v = xb[i * 3 + c] - (c == 0 ? cx : (c == 1 ? cy : cz));
    else if (c < 131) v = f2[((size_t)b * 64 + i) * 128 + (c - 3)];
    else v = 0.f;
    xld[j][c] = v;
  }
  __syncthreads();
  float acc[16];
  // layer4: cin 132(pad), cout 256; thread t: o=t, all 16 j
  {
    float bias = bb4[t];
    for (int jj = 0; jj < 16; ++jj) acc[jj] = bias;
    for (int c4 = 0; c4 < 33; ++c4) {
      int c = c4 * 4;
      float w0 = wT4[(c + 0) * 256 + t], w1 = wT4[(c + 1) * 256 + t];
      float w2 = wT4[(c + 2) * 256 + t], w3 = wT4[(c + 3) * 256 + t];
      for (int jj = 0; jj < 16; ++jj) {
        float4 x4 = *reinterpret_cast<const float4*>(&xld[jj][c]);
        acc[jj] = fmaf(w0, x4.x, fmaf(w1, x4.y, fmaf(w2, x4.z, fmaf(w3, x4.w, acc[jj]))));
      }
    }
    for (int jj = 0; jj < 16; ++jj) h1[jj][t] = fmaxf(acc[jj], 0.f);
  }
  __syncthreads();
  // layer5: cin 256, cout 256, fused max, write final output (b, c, s)
  {
    const float* wT5 = wT4 + 33792;
    float bias = bb4[256 + t];
    for (int jj = 0; jj < 16; ++jj) acc[jj] = bias;
    for (int c4 = 0; c4 < 64; ++c4) {
      int c = c4 * 4;
      float w0 = wT5[(c + 0) * 256 + t], w1 = wT5[(c + 1) * 256 + t];
      float w2 = wT5[(c + 2) * 256 + t], w3 = wT5[(c + 3) * 256 + t];
      for (int jj = 0; jj < 16; ++jj) {
        float4 x4 = *reinterpret_cast<const float4*>(&h1[jj][c]);
        acc[jj] = fmaf(w0, x4.x, fmaf(w1, x4.y, fmaf(w2, x4.z, fmaf(w3, x4.w, acc[jj]))));
      }
    }
    float mx = -1e30f;
    for (int jj = 0; jj < 16; ++jj) mx = fmaxf(mx, fmaxf(acc[jj], 0.f));
    out[((size_t)b * 256 + t) * 32 + s] = mx;
  }
}

extern "C" void kernel_launch(void* const* d_in, const int* in_sizes, int n_in,
                              void* d_out, int out_size, void* d_ws, size_t ws_size,
                              hipStream_t stream) {
  (void)in_sizes; (void)n_in; (void)out_size; (void)ws_size;
  const float* pc = (const float*)d_in[0];
  const float *W[6], *G[6], *BE[6], *RM[6], *RV[6];
  for (int l = 0; l < 6; ++l) {
    W[l]  = (const float*)d_in[1 + 5 * l + 0];
    G[l]  = (const float*)d_in[1 + 5 * l + 1];
    BE[l] = (const float*)d_in[1 + 5 * l + 2];
    RM[l] = (const float*)d_in[1 + 5 * l + 3];
    RV[l] = (const float*)d_in[1 + 5 * l + 4];
  }
  float* ws = (float*)d_ws;
  float* wbuf = ws + 0;
  float* bbuf = ws + 126848;
  float* xyz1 = ws + 131072;
  float* xyz2 = ws + 155648;
  float* xyz3 = ws + 167936;
  float* f1   = ws + 174080;
  float* f2   = ws + 698368;
  float* out  = (float*)d_out;

  const int cin[6]  = {9, 32, 67, 128, 131, 256};
  const int cinp[6] = {12, 32, 68, 128, 132, 256};
  const int cout[6] = {32, 64, 128, 128, 256, 256};
  const int woff[6] = {0, 384, 2432, 11136, 27520, 61312};
  const int boff[6] = {0, 32, 96, 224, 352, 608};
  for (int l = 0; l < 6; ++l) {
    int tot = cout[l] * cinp[l];
    prep_layer<<<(tot + 255) / 256, 256, 0, stream>>>(
        W[l], G[l], BE[l], RM[l], RV[l], wbuf + woff[l], bbuf + boff[l],
        cin[l], cinp[l], cout[l]);
  }
  fps1_kernel<<<64, 256, 0, stream>>>(pc, xyz1);
  group1_kernel<<<dim3(128, 64), 64, 0, stream>>>(pc, xyz1, wbuf, bbuf, f1);
  fps2_kernel<<<64, 64, 0, stream>>>(xyz1, xyz2);
  group2_kernel<<<dim3(64, 64), 256, 0, stream>>>(xyz1, xyz2, f1, wbuf + 2432, bbuf + 96, f2);
  fps3_kernel<<<64, 64, 0, stream>>>(xyz2, xyz3);
  group3_kernel<<<dim3(32, 64), 256, 0, stream>>>(xyz2, xyz3, f2, wbuf + 27520, bbuf + 352, out);
}

// Round 3
// 589.377 us; speedup vs baseline: 1.0690x; 1.0690x over previous
//
#include <hip/hip_runtime.h>
#include <math.h>

// Stage1: N=4096 -> np=128, r=0.02, ns=32, layers (9->32), (32->64)
// Stage2: N=128  -> np=64,  r=0.04, ns=32, layers (67->128), (128->128)
// Stage3: N=64   -> np=32,  r=0.08, ns=16, layers (131->256), (256->256)
//
// ws layout (floats):
//   wT (transposed, padded, BN-scale folded): [0, 126848)
//     L0 off 0 (12x32)  L1 off 384 (32x64)  L2 off 2432 (68x128)
//     L3 off 11136 (128x128)  L4 off 27520 (132x256)  L5 off 61312 (256x256)
//   bias: [126848, 127712)  offs 0,32,96,224,352,608
//   xyz1 131072 (64*128*3)  xyz2 155648 (64*64*3)  xyz3 167936 (64*32*3)
//   f1 174080 (64*128*64)   f2 698368 (64*64*128)

struct PrepArgs {
  const float* w[6]; const float* g[6]; const float* be[6];
  const float* rm[6]; const float* rv[6];
};

__global__ __launch_bounds__(256) void prep_all(PrepArgs a, float* __restrict__ wT,
                                                float* __restrict__ bias) {
  const int woff[7] = {0, 384, 2432, 11136, 27520, 61312, 126848};
  const int cin[6]  = {9, 32, 67, 128, 131, 256};
  const int osh[6]  = {5, 6, 7, 7, 8, 8};  // log2 cout
  const int boff[7] = {0, 32, 96, 224, 352, 608, 864};
  int i = blockIdx.x * blockDim.x + threadIdx.x;
  if (i < 126848) {
    int l = 0;
    while (i >= woff[l + 1]) ++l;
    int local = i - woff[l];
    int c = local >> osh[l];
    int o = local & ((1 << osh[l]) - 1);
    float sc = a.g[l][o] / sqrtf(a.rv[l][o] + 1e-5f);
    wT[i] = (c < cin[l]) ? a.w[l][o * cin[l] + c] * sc : 0.f;
  } else if (i < 127712) {
    int j = i - 126848;
    int l = 0;
    while (j >= boff[l + 1]) ++l;
    int o = j - boff[l];
    float sc = a.g[l][o] / sqrtf(a.rv[l][o] + 1e-5f);
    bias[j] = a.be[l][o] - a.rm[l][o] * sc;
  }
}

// exact (non-contracted) squared distance, matching numpy op order
__device__ __forceinline__ float dist2_exact(float px, float py, float pz,
                                             float cx, float cy, float cz) {
  float dx = px - cx, dy = py - cy, dz = pz - cz;
  return __fadd_rn(__fadd_rn(__fmul_rn(dx, dx), __fmul_rn(dy, dy)), __fmul_rn(dz, dz));
}

// ---------------- FPS stage 1: N=4096, npoint=128 ----------------
__global__ __launch_bounds__(256) void fps1_kernel(const float* __restrict__ pc,
                                                   float* __restrict__ newxyz) {
  int b = blockIdx.x;
  const float* xb = pc + (size_t)b * 4096 * 3;
  float* out = newxyz + (size_t)b * 128 * 3;
  __shared__ float s_pts[4096 * 3];
  __shared__ float s_val[2][4];
  __shared__ int s_idx[2][4];
  int t = threadIdx.x;
  for (int e = t; e < 4096 * 3; e += 256) s_pts[e] = xb[e];
  __syncthreads();
  float px[16], py[16], pz[16], dist[16];
  for (int k = 0; k < 16; ++k) {
    int i = k * 256 + t;
    px[k] = s_pts[i * 3]; py[k] = s_pts[i * 3 + 1]; pz[k] = s_pts[i * 3 + 2];
    dist[k] = 1e10f;
  }
  float cx = s_pts[0], cy = s_pts[1], cz = s_pts[2];
  if (t == 0) { out[0] = cx; out[1] = cy; out[2] = cz; }
  int lane = t & 63, wv = t >> 6;
  for (int it = 1; it < 128; ++it) {
    float bv = -1.f; int bi = 0;
    for (int k = 0; k < 16; ++k) {
      float d = dist2_exact(px[k], py[k], pz[k], cx, cy, cz);
      float nd = fminf(dist[k], d);
      dist[k] = nd;
      if (nd > bv) { bv = nd; bi = k * 256 + t; }
    }
    for (int off = 32; off >= 1; off >>= 1) {
      float ov = __shfl_down(bv, (unsigned)off, 64);
      int oi = __shfl_down(bi, (unsigned)off, 64);
      if (ov > bv || (ov == bv && oi < bi)) { bv = ov; bi = oi; }
    }
    int pb = it & 1;
    if (lane == 0) { s_val[pb][wv] = bv; s_idx[pb][wv] = bi; }
    __syncthreads();
    float v0 = s_val[pb][0]; int i0 = s_idx[pb][0];
    for (int w = 1; w < 4; ++w) {
      float v = s_val[pb][w]; int ii = s_idx[pb][w];
      if (v > v0 || (v == v0 && ii < i0)) { v0 = v; i0 = ii; }
    }
    cx = s_pts[i0 * 3]; cy = s_pts[i0 * 3 + 1]; cz = s_pts[i0 * 3 + 2];
    if (t == 0) { out[it * 3] = cx; out[it * 3 + 1] = cy; out[it * 3 + 2] = cz; }
  }
}

// ---------------- FPS stage 2: N=128, npoint=64, one wave ----------------
__global__ __launch_bounds__(64) void fps2_kernel(const float* __restrict__ xyz1,
                                                  float* __restrict__ out_xyz) {
  int b = blockIdx.x;
  const float* xb = xyz1 + (size_t)b * 128 * 3;
  float* out = out_xyz + (size_t)b * 64 * 3;
  int t = threadIdx.x;
  float px[2], py[2], pz[2], dist[2];
  for (int k = 0; k < 2; ++k) {
    int i = k * 64 + t;
    px[k] = xb[i * 3]; py[k] = xb[i * 3 + 1]; pz[k] = xb[i * 3 + 2];
    dist[k] = 1e10f;
  }
  float cx = __shfl(px[0], 0, 64), cy = __shfl(py[0], 0, 64), cz = __shfl(pz[0], 0, 64);
  if (t == 0) { out[0] = cx; out[1] = cy; out[2] = cz; }
  for (int it = 1; it < 64; ++it) {
    float bv = -1.f; int bi = 0;
    for (int k = 0; k < 2; ++k) {
      float d = dist2_exact(px[k], py[k], pz[k], cx, cy, cz);
      dist[k] = fminf(dist[k], d);
      if (dist[k] > bv) { bv = dist[k]; bi = k * 64 + t; }
    }
    for (int off = 32; off >= 1; off >>= 1) {
      float ov = __shfl_down(bv, (unsigned)off, 64);
      int oi = __shfl_down(bi, (unsigned)off, 64);
      if (ov > bv || (ov == bv && oi < bi)) { bv = ov; bi = oi; }
    }
    int sel = __shfl(bi, 0, 64);
    int sl = sel & 63, sk = sel >> 6;
    float qx = sk ? px[1] : px[0], qy = sk ? py[1] : py[0], qz = sk ? pz[1] : pz[0];
    cx = __shfl(qx, sl, 64); cy = __shfl(qy, sl, 64); cz = __shfl(qz, sl, 64);
    if (t == 0) { out[it * 3] = cx; out[it * 3 + 1] = cy; out[it * 3 + 2] = cz; }
  }
}

// ---------------- FPS stage 3: N=64, npoint=32, one wave ----------------
__global__ __launch_bounds__(64) void fps3_kernel(const float* __restrict__ xyz2,
                                                  float* __restrict__ out_xyz) {
  int b = blockIdx.x;
  const float* xb = xyz2 + (size_t)b * 64 * 3;
  float* out = out_xyz + (size_t)b * 32 * 3;
  int t = threadIdx.x;
  float px = xb[t * 3], py = xb[t * 3 + 1], pz = xb[t * 3 + 2];
  float dist = 1e10f;
  float cx = __shfl(px, 0, 64), cy = __shfl(py, 0, 64), cz = __shfl(pz, 0, 64);
  if (t == 0) { out[0] = cx; out[1] = cy; out[2] = cz; }
  for (int it = 1; it < 32; ++it) {
    float d = dist2_exact(px, py, pz, cx, cy, cz);
    dist = fminf(dist, d);
    float bv = dist; int bi = t;
    for (int off = 32; off >= 1; off >>= 1) {
      float ov = __shfl_down(bv, (unsigned)off, 64);
      int oi = __shfl_down(bi, (unsigned)off, 64);
      if (ov > bv || (ov == bv && oi < bi)) { bv = ov; bi = oi; }
    }
    int sel = __shfl(bi, 0, 64);
    cx = __shfl(px, sel, 64); cy = __shfl(py, sel, 64); cz = __shfl(pz, sel, 64);
    if (t == 0) { out[it * 3] = cx; out[it * 3 + 1] = cy; out[it * 3 + 2] = cz; }
  }
}

// ---------------- ball query (single wave) ----------------
__device__ __forceinline__ int ball_query_wave(const float* __restrict__ xb, int N,
                                               float cx, float cy, float cz, float r2,
                                               int nsample, int* list, int lane) {
  int cnt = 0;
  for (int base = 0; base < N && cnt < nsample; base += 64) {
    int i = base + lane;
    float d2 = dist2_exact(xb[i * 3], xb[i * 3 + 1], xb[i * 3 + 2], cx, cy, cz);
    bool in = d2 < r2;
    unsigned long long m = __ballot(in);
    if (in) {
      int pos = cnt + __popcll(m & ((1ull << lane) - 1ull));
      if (pos < nsample) list[pos] = i;
    }
    cnt += __popcll(m);
  }
  return cnt;
}

#define FMA4(aq, w0, w1, w2, w3, xv, comp)                                   \
  aq = fmaf(w0.comp, xv.x, fmaf(w1.comp, xv.y, fmaf(w2.comp, xv.z,           \
       fmaf(w3.comp, xv.w, aq))))

// ---------------- group+MLP stage 1: 8 groups/block, 2 chunks of 128 j -------
// LDS: W0s 1536 + W1s 8192 + X 6144 + h1 18432 + pm1 4096 + misc ~ 39.6 KB
__global__ __launch_bounds__(256) void group1_kernel(const float* __restrict__ pc,
    const float* __restrict__ newxyz1, const float* __restrict__ wbuf,
    const float* __restrict__ bbuf, float* __restrict__ f1) {
  __shared__ float W0s[384];       // [12][32]
  __shared__ float W1s[2048];      // [32][64]
  __shared__ float X[128 * 12];
  __shared__ float h1[128 * 36];   // stride 36
  __shared__ float pm1[16 * 64];
  __shared__ float ctr[24];
  __shared__ int lst[256];         // [8][32]
  __shared__ int cnts[8];
  int t = threadIdx.x;
  int b = blockIdx.y, s0 = blockIdx.x * 8;
  const float* xb = pc + (size_t)b * 4096 * 3;
  for (int e = t; e < 384; e += 256) W0s[e] = wbuf[e];
  for (int e = t; e < 2048; e += 256) W1s[e] = wbuf[384 + e];
  int lane = t & 63, wv = t >> 6;
  for (int k = 0; k < 2; ++k) {
    int g = wv * 2 + k;
    const float* c3 = newxyz1 + ((size_t)b * 128 + s0 + g) * 3;
    float cx = c3[0], cy = c3[1], cz = c3[2];
    if (lane == 0) { ctr[g * 3] = cx; ctr[g * 3 + 1] = cy; ctr[g * 3 + 2] = cz; }
    int cnt = ball_query_wave(xb, 4096, cx, cy, cz, 4.0e-4f, 32, lst + g * 32, lane);
    if (lane == 0) cnts[g] = cnt;
  }
  __syncthreads();
  { int g = t >> 5, q = t & 31; if (q >= cnts[g]) lst[t] = (cnts[g] > 0) ? lst[g * 32] : 0; }
  __syncthreads();
  int o_l0 = t & 31, jb0 = (t >> 5) * 16;
  float w0v[12];
  #pragma unroll
  for (int c = 0; c < 12; ++c) w0v[c] = W0s[c * 32 + o_l0];
  float b0 = bbuf[o_l0];
  int ot1 = t & 15, jt1 = t >> 4;
  int o0 = ot1 * 4, j0 = jt1 * 8;
  float bias1[4];
  #pragma unroll
  for (int r = 0; r < 4; ++r) bias1[r] = bbuf[32 + o0 + r];
  for (int chunk = 0; chunk < 2; ++chunk) {
    if (t < 128) {
      int j = t;
      int g = chunk * 4 + (j >> 5);
      int i = lst[g * 32 + (j & 31)];
      float px = xb[i * 3], py = xb[i * 3 + 1], pz = xb[i * 3 + 2];
      float4 v0, v1, v2;
      v0.x = px - ctr[g * 3]; v0.y = py - ctr[g * 3 + 1]; v0.z = pz - ctr[g * 3 + 2];
      v0.w = px; v1.x = py; v1.y = pz; v1.z = px; v1.w = py;
      v2.x = pz; v2.y = 0.f; v2.z = 0.f; v2.w = 0.f;
      *reinterpret_cast<float4*>(&X[j * 12 + 0]) = v0;
      *reinterpret_cast<float4*>(&X[j * 12 + 4]) = v1;
      *reinterpret_cast<float4*>(&X[j * 12 + 8]) = v2;
    }
    __syncthreads();
    // layer0: o = t&31, 16 j per thread
    for (int jj = 0; jj < 16; ++jj) {
      int j = jb0 + jj;
      float4 x0 = *reinterpret_cast<const float4*>(&X[j * 12 + 0]);
      float4 x1 = *reinterpret_cast<const float4*>(&X[j * 12 + 4]);
      float4 x2 = *reinterpret_cast<const float4*>(&X[j * 12 + 8]);
      float a = b0;
      a = fmaf(w0v[0], x0.x, a); a = fmaf(w0v[1], x0.y, a);
      a = fmaf(w0v[2], x0.z, a); a = fmaf(w0v[3], x0.w, a);
      a = fmaf(w0v[4], x1.x, a); a = fmaf(w0v[5], x1.y, a);
      a = fmaf(w0v[6], x1.z, a); a = fmaf(w0v[7], x1.w, a);
      a = fmaf(w0v[8], x2.x, a); a = fmaf(w0v[9], x2.y, a);
      a = fmaf(w0v[10], x2.z, a); a = fmaf(w0v[11], x2.w, a);
      h1[j * 36 + o_l0] = fmaxf(a, 0.f);
    }
    __syncthreads();
    // layer1: tile 4o x 8j over [64 o][128 j], K=32
    float acc[8][4];
    #pragma unroll
    for (int q = 0; q < 8; ++q)
      #pragma unroll
      for (int r = 0; r < 4; ++r) acc[q][r] = bias1[r];
    for (int c4 = 0; c4 < 8; ++c4) {
      int c = c4 * 4;
      float4 w0 = *reinterpret_cast<const float4*>(&W1s[(c + 0) * 64 + o0]);
      float4 w1 = *reinterpret_cast<const float4*>(&W1s[(c + 1) * 64 + o0]);
      float4 w2 = *reinterpret_cast<const float4*>(&W1s[(c + 2) * 64 + o0]);
      float4 w3 = *reinterpret_cast<const float4*>(&W1s[(c + 3) * 64 + o0]);
      #pragma unroll
      for (int q = 0; q < 8; ++q) {
        float4 xv = *reinterpret_cast<const float4*>(&h1[(j0 + q) * 36 + c]);
        FMA4(acc[q][0], w0, w1, w2, w3, xv, x);
        FMA4(acc[q][1], w0, w1, w2, w3, xv, y);
        FMA4(acc[q][2], w0, w1, w2, w3, xv, z);
        FMA4(acc[q][3], w0, w1, w2, w3, xv, w);
      }
    }
    {
      float m[4] = {-1e30f, -1e30f, -1e30f, -1e30f};
      #pragma unroll
      for (int q = 0; q < 8; ++q)
        #pragma unroll
        for (int r = 0; r < 4; ++r) m[r] = fmaxf(m[r], acc[q][r]);
      float4 mv; mv.x = m[0]; mv.y = m[1]; mv.z = m[2]; mv.w = m[3];
      *reinterpret_cast<float4*>(&pm1[jt1 * 64 + o0]) = mv;
    }
    __syncthreads();
    {
      int o = t & 63, g = t >> 6;
      float v = pm1[(4 * g + 0) * 64 + o];
      v = fmaxf(v, pm1[(4 * g + 1) * 64 + o]);
      v = fmaxf(v, pm1[(4 * g + 2) * 64 + o]);
      v = fmaxf(v, pm1[(4 * g + 3) * 64 + o]);
      f1[((size_t)b * 128 + s0 + chunk * 4 + g) * 64 + o] = fmaxf(v, 0.f);
    }
    __syncthreads();
  }
}

// ---------------- group+MLP stage 2: 8 groups/block, 4 chunks of 64 j --------
// LDS: Xs 17408 + Hs 33792 + pm 4096 + misc ~ 56.4 KB. Weights from global.
__global__ __launch_bounds__(256) void group2_kernel(const float* __restrict__ xyz1,
    const float* __restrict__ newxyz2, const float* __restrict__ f1,
    const float* __restrict__ wbuf, const float* __restrict__ bbuf,
    float* __restrict__ f2) {
  __shared__ float Xs[64 * 68];
  __shared__ float Hs[64 * 132];
  __shared__ float pm[8 * 128];
  __shared__ float ctr[24];
  __shared__ int lst[256];  // [8][32]
  __shared__ int cnts[8];
  int t = threadIdx.x;
  int b = blockIdx.y, s0 = blockIdx.x * 8;
  const float* xb = xyz1 + (size_t)b * 128 * 3;
  const float* W2g = wbuf + 2432;
  const float* W3g = wbuf + 11136;
  int lane = t & 63, wv = t >> 6;
  for (int k = 0; k < 2; ++k) {
    int g = wv * 2 + k;
    const float* c3 = newxyz2 + ((size_t)b * 64 + s0 + g) * 3;
    float cx = c3[0], cy = c3[1], cz = c3[2];
    if (lane == 0) { ctr[g * 3] = cx; ctr[g * 3 + 1] = cy; ctr[g * 3 + 2] = cz; }
    int cnt = ball_query_wave(xb, 128, cx, cy, cz, 1.6e-3f, 32, lst + g * 32, lane);
    if (lane == 0) cnts[g] = cnt;
  }
  __syncthreads();
  { int g = t >> 5, q = t & 31; if (q >= cnts[g]) lst[t] = (cnts[g] > 0) ? lst[g * 32] : 0; }
  __syncthreads();
  int ot = t & 31, jt = t >> 5;
  int o0 = ot * 4, j0 = jt * 8;
  float bias2[4], bias3[4];
  #pragma unroll
  for (int r = 0; r < 4; ++r) {
    bias2[r] = bbuf[96 + o0 + r];
    bias3[r] = bbuf[224 + o0 + r];
  }
  for (int chunk = 0; chunk < 4; ++chunk) {
    for (int e = t; e < 64 * 17; e += 256) {
      int j = e & 63, q = e >> 6;
      int g = chunk * 2 + (j >> 5);
      int i = lst[g * 32 + (j & 31)];
      const float* f1r = f1 + ((size_t)b * 128 + i) * 64;
      int c = q * 4;
      float vv[4];
      #pragma unroll
      for (int u = 0; u < 4; ++u) {
        int cc = c + u;
        float x;
        if (cc < 3) x = xb[i * 3 + cc] - ctr[g * 3 + cc];
        else if (cc < 67) x = f1r[cc - 3];
        else x = 0.f;
        vv[u] = x;
      }
      float4 v; v.x = vv[0]; v.y = vv[1]; v.z = vv[2]; v.w = vv[3];
      *reinterpret_cast<float4*>(&Xs[j * 68 + c]) = v;
    }
    __syncthreads();
    float acc[8][4];
    // layer2: [128 o x 64 j], K=68
    #pragma unroll
    for (int q = 0; q < 8; ++q)
      #pragma unroll
      for (int r = 0; r < 4; ++r) acc[q][r] = bias2[r];
    for (int c4 = 0; c4 < 17; ++c4) {
      int c = c4 * 4;
      float4 w0 = *reinterpret_cast<const float4*>(&W2g[(c + 0) * 128 + o0]);
      float4 w1 = *reinterpret_cast<const float4*>(&W2g[(c + 1) * 128 + o0]);
      float4 w2 = *reinterpret_cast<const float4*>(&W2g[(c + 2) * 128 + o0]);
      float4 w3 = *reinterpret_cast<const float4*>(&W2g[(c + 3) * 128 + o0]);
      #pragma unroll
      for (int q = 0; q < 8; ++q) {
        float4 xv = *reinterpret_cast<const float4*>(&Xs[(j0 + q) * 68 + c]);
        FMA4(acc[q][0], w0, w1, w2, w3, xv, x);
        FMA4(acc[q][1], w0, w1, w2, w3, xv, y);
        FMA4(acc[q][2], w0, w1, w2, w3, xv, z);
        FMA4(acc[q][3], w0, w1, w2, w3, xv, w);
      }
    }
    #pragma unroll
    for (int q = 0; q < 8; ++q) {
      float4 hv;
      hv.x = fmaxf(acc[q][0], 0.f); hv.y = fmaxf(acc[q][1], 0.f);
      hv.z = fmaxf(acc[q][2], 0.f); hv.w = fmaxf(acc[q][3], 0.f);
      *reinterpret_cast<float4*>(&Hs[(j0 + q) * 132 + o0]) = hv;
    }
    __syncthreads();
    // layer3: [128 o x 64 j], K=128
    #pragma unroll
    for (int q = 0; q < 8; ++q)
      #pragma unroll
      for (int r = 0; r < 4; ++r) acc[q][r] = bias3[r];
    for (int c4 = 0; c4 < 32; ++c4) {
      int c = c4 * 4;
      float4 w0 = *reinterpret_cast<const float4*>(&W3g[(c + 0) * 128 + o0]);
      float4 w1 = *reinterpret_cast<const float4*>(&W3g[(c + 1) * 128 + o0]);
      float4 w2 = *reinterpret_cast<const float4*>(&W3g[(c + 2) * 128 + o0]);
      float4 w3 = *reinterpret_cast<const float4*>(&W3g[(c + 3) * 128 + o0]);
      #pragma unroll
      for (int q = 0; q < 8; ++q) {
        float4 xv = *reinterpret_cast<const float4*>(&Hs[(j0 + q) * 132 + c]);
        FMA4(acc[q][0], w0, w1, w2, w3, xv, x);
        FMA4(acc[q][1], w0, w1, w2, w3, xv, y);
        FMA4(acc[q][2], w0, w1, w2, w3, xv, z);
        FMA4(acc[q][3], w0, w1, w2, w3, xv, w);
      }
    }
    {
      float m[4] = {-1e30f, -1e30f, -1e30f, -1e30f};
      #pragma unroll
      for (int q = 0; q < 8; ++q)
        #pragma unroll
        for (int r = 0; r < 4; ++r) m[r] = fmaxf(m[r], acc[q][r]);
      float4 mv; mv.x = m[0]; mv.y = m[1]; mv.z = m[2]; mv.w = m[3];
      *reinterpret_cast<float4*>(&pm[jt * 128 + o0]) = mv;
    }
    __syncthreads();
    {
      int o = t & 127, h = t >> 7;
      float v = pm[(4 * h + 0) * 128 + o];
      v = fmaxf(v, pm[(4 * h + 1) * 128 + o]);
      v = fmaxf(v, pm[(4 * h + 2) * 128 + o]);
      v = fmaxf(v, pm[(4 * h + 3) * 128 + o]);
      f2[((size_t)b * 64 + s0 + chunk * 2 + h) * 128 + o] = fmaxf(v, 0.f);
    }
    __syncthreads();
  }
}

// ---------------- group+MLP stage 3: 4 groups/block, 2 chunks of 32 j --------
// LDS: X3 16896 + Hs3 33280 + pm3 4096 + misc ~ 54.9 KB. Weights from global.
__global__ __launch_bounds__(256) void group3_kernel(const float* __restrict__ xyz2,
    const float* __restrict__ newxyz3, const float* __restrict__ f2,
    const float* __restrict__ wbuf, const float* __restrict__ bbuf,
    float* __restrict__ out) {
  __shared__ float X3[32 * 132];
  __shared__ float Hs3[32 * 260];
  __shared__ float pm3[4 * 256];
  __shared__ float ctr[12];
  __shared__ int lst[64];  // [4][16]
  __shared__ int cnts[4];
  int t = threadIdx.x;
  int b = blockIdx.y, s0 = blockIdx.x * 4;
  const float* xb = xyz2 + (size_t)b * 64 * 3;
  const float* W4g = wbuf + 27520;
  const float* W5g = wbuf + 61312;
  int lane = t & 63, wv = t >> 6;
  {
    int g = wv;
    const float* c3 = newxyz3 + ((size_t)b * 32 + s0 + g) * 3;
    float cx = c3[0], cy = c3[1], cz = c3[2];
    if (lane == 0) { ctr[g * 3] = cx; ctr[g * 3 + 1] = cy; ctr[g * 3 + 2] = cz; }
    int cnt = ball_query_wave(xb, 64, cx, cy, cz, 6.4e-3f, 16, lst + g * 16, lane);
    if (lane == 0) cnts[g] = cnt;
  }
  __syncthreads();
  if (t < 64) { int g = t >> 4, q = t & 15; if (q >= cnts[g]) lst[t] = (cnts[g] > 0) ? lst[g * 16] : 0; }
  __syncthreads();
  int ot = t & 63, jt = t >> 6;
  int o0 = ot * 4, j0 = jt * 8;
  float bias4[4], bias5[4];
  #pragma unroll
  for (int r = 0; r < 4; ++r) {
    bias4[r] = bbuf[352 + o0 + r];
    bias5[r] = bbuf[608 + o0 + r];
  }
  for (int chunk = 0; chunk < 2; ++chunk) {
    for (int e = t; e < 32 * 33; e += 256) {
      int j = e & 31, q = e >> 5;  // q 0..32
      int g = chunk * 2 + (j >> 4);
      int i = lst[g * 16 + (j & 15)];
      const float* f2r = f2 + ((size_t)b * 64 + i) * 128;
      int c = q * 4;
      float vv[4];
      #pragma unroll
      for (int u = 0; u < 4; ++u) {
        int cc = c + u;
        float x;
        if (cc < 3) x = xb[i * 3 + cc] - ctr[g * 3 + cc];
        else if (cc < 131) x = f2r[cc - 3];
        else x = 0.f;
        vv[u] = x;
      }
      float4 v; v.x = vv[0]; v.y = vv[1]; v.z = vv[2]; v.w = vv[3];
      *reinterpret_cast<float4*>(&X3[j * 132 + c]) = v;
    }
    __syncthreads();
    float acc[8][4];
    // layer4: [256 o x 32 j], K=132
    #pragma unroll
    for (int q = 0; q < 8; ++q)
      #pragma unroll
      for (int r = 0; r < 4; ++r) acc[q][r] = bias4[r];
    for (int c4 = 0; c4 < 33; ++c4) {
      int c = c4 * 4;
      float4 w0 = *reinterpret_cast<const float4*>(&W4g[(c + 0) * 256 + o0]);
      float4 w1 = *reinterpret_cast<const float4*>(&W4g[(c + 1) * 256 + o0]);
      float4 w2 = *reinterpret_cast<const float4*>(&W4g[(c + 2) * 256 + o0]);
      float4 w3 = *reinterpret_cast<const float4*>(&W4g[(c + 3) * 256 + o0]);
      #pragma unroll
      for (int q = 0; q < 8; ++q) {
        float4 xv = *reinterpret_cast<const float4*>(&X3[(j0 + q) * 132 + c]);
        FMA4(acc[q][0], w0, w1, w2, w3, xv, x);
        FMA4(acc[q][1], w0, w1, w2, w3, xv, y);
        FMA4(acc[q][2], w0, w1, w2, w3, xv, z);
        FMA4(acc[q][3], w0, w1, w2, w3, xv, w);
      }
    }
    #pragma unroll
    for (int q = 0; q < 8; ++q) {
      float4 hv;
      hv.x = fmaxf(acc[q][0], 0.f); hv.y = fmaxf(acc[q][1], 0.f);
      hv.z = fmaxf(acc[q][2], 0.f); hv.w = fmaxf(acc[q][3], 0.f);
      *reinterpret_cast<float4*>(&Hs3[(j0 + q) * 260 + o0]) = hv;
    }
    __syncthreads();
    // layer5: [256 o x 32 j], K=256
    #pragma unroll
    for (int q = 0; q < 8; ++q)
      #pragma unroll
      for (int r = 0; r < 4; ++r) acc[q][r] = bias5[r];
    for (int c4 = 0; c4 < 64; ++c4) {
      int c = c4 * 4;
      float4 w0 = *reinterpret_cast<const float4*>(&W5g[(c + 0) * 256 + o0]);
      float4 w1 = *reinterpret_cast<const float4*>(&W5g[(c + 1) * 256 + o0]);
      float4 w2 = *reinterpret_cast<const float4*>(&W5g[(c + 2) * 256 + o0]);
      float4 w3 = *reinterpret_cast<const float4*>(&W5g[(c + 3) * 256 + o0]);
      #pragma unroll
      for (int q = 0; q < 8; ++q) {
        float4 xv = *reinterpret_cast<const float4*>(&Hs3[(j0 + q) * 260 + c]);
        FMA4(acc[q][0], w0, w1, w2, w3, xv, x);
        FMA4(acc[q][1], w0, w1, w2, w3, xv, y);
        FMA4(acc[q][2], w0, w1, w2, w3, xv, z);
        FMA4(acc[q][3], w0, w1, w2, w3, xv, w);
      }
    }
    {
      float m[4] = {-1e30f, -1e30f, -1e30f, -1e30f};
      #pragma unroll
      for (int q = 0; q < 8; ++q)
        #pragma unroll
        for (int r = 0; r < 4; ++r) m[r] = fmaxf(m[r], acc[q][r]);
      float4 mv; mv.x = m[0]; mv.y = m[1]; mv.z = m[2]; mv.w = m[3];
      *reinterpret_cast<float4*>(&pm3[jt * 256 + o0]) = mv;
    }
    __syncthreads();
    {
      int o = t;
      #pragma unroll
      for (int g = 0; g < 2; ++g) {
        float v = fmaxf(pm3[(2 * g) * 256 + o], pm3[(2 * g + 1) * 256 + o]);
        out[((size_t)b * 256 + o) * 32 + s0 + chunk * 2 + g] = fmaxf(v, 0.f);
      }
    }
    __syncthreads();
  }
}

extern "C" void kernel_launch(void* const* d_in, const int* in_sizes, int n_in,
                              void* d_out, int out_size, void* d_ws, size_t ws_size,
                              hipStream_t stream) {
  (void)in_sizes; (void)n_in; (void)out_size; (void)ws_size;
  const float* pc = (const float*)d_in[0];
  PrepArgs pa;
  for (int l = 0; l < 6; ++l) {
    pa.w[l]  = (const float*)d_in[1 + 5 * l + 0];
    pa.g[l]  = (const float*)d_in[1 + 5 * l + 1];
    pa.be[l] = (const float*)d_in[1 + 5 * l + 2];
    pa.rm[l] = (const float*)d_in[1 + 5 * l + 3];
    pa.rv[l] = (const float*)d_in[1 + 5 * l + 4];
  }
  float* ws = (float*)d_ws;
  float* wbuf = ws + 0;
  float* bbuf = ws + 126848;
  float* xyz1 = ws + 131072;
  float* xyz2 = ws + 155648;
  float* xyz3 = ws + 167936;
  float* f1   = ws + 174080;
  float* f2   = ws + 698368;
  float* out  = (float*)d_out;

  prep_all<<<499, 256, 0, stream>>>(pa, wbuf, bbuf);
  fps1_kernel<<<64, 256, 0, stream>>>(pc, xyz1);
  group1_kernel<<<dim3(16, 64), 256, 0, stream>>>(pc, xyz1, wbuf, bbuf, f1);
  fps2_kernel<<<64, 64, 0, stream>>>(xyz1, xyz2);
  group2_kernel<<<dim3(8, 64), 256, 0, stream>>>(xyz1, xyz2, f1, wbuf, bbuf, f2);
  fps3_kernel<<<64, 64, 0, stream>>>(xyz2, xyz3);
  group3_kernel<<<dim3(8, 64), 256, 0, stream>>>(xyz2, xyz3, f2, wbuf, bbuf, out);
}

// Round 4
// 518.286 us; speedup vs baseline: 1.2156x; 1.1372x over previous
//
#include <hip/hip_runtime.h>
#include <math.h>

// Stage1: N=4096 -> np=128, r=0.02, ns=32, layers (9->32), (32->64)
// Stage2: N=128  -> np=64,  r=0.04, ns=32, layers (67->128), (128->128)
// Stage3: N=64   -> np=32,  r=0.08, ns=16, layers (131->256), (256->256)
//
// ws layout (floats):
//   wT (transposed, padded, BN-scale folded): [0, 126848)
//     L0 off 0 (12x32)  L1 off 384 (32x64)  L2 off 2432 (68x128)
//     L3 off 11136 (128x128)  L4 off 27520 (132x256)  L5 off 61312 (256x256)
//   bias: [126848, 127712)  offs 0,32,96,224,352,608
//   xyz1 131072 (64*128*3)  xyz2 155648 (64*64*3)  xyz3 167936 (64*32*3)
//   f1 174080 (64*128*64)   f2 698368 (64*64*128)

struct PrepArgs {
  const float* w[6]; const float* g[6]; const float* be[6];
  const float* rm[6]; const float* rv[6];
};

__device__ __forceinline__ void prep_body(const PrepArgs& a, float* __restrict__ wT,
                                          float* __restrict__ bias, int i) {
  const int woff[7] = {0, 384, 2432, 11136, 27520, 61312, 126848};
  const int cin[6]  = {9, 32, 67, 128, 131, 256};
  const int osh[6]  = {5, 6, 7, 7, 8, 8};  // log2 cout
  const int boff[7] = {0, 32, 96, 224, 352, 608, 864};
  if (i < 126848) {
    int l = 0;
    while (i >= woff[l + 1]) ++l;
    int local = i - woff[l];
    int c = local >> osh[l];
    int o = local & ((1 << osh[l]) - 1);
    float sc = a.g[l][o] / sqrtf(a.rv[l][o] + 1e-5f);
    wT[i] = (c < cin[l]) ? a.w[l][o * cin[l] + c] * sc : 0.f;
  } else if (i < 127712) {
    int j = i - 126848;
    int l = 0;
    while (j >= boff[l + 1]) ++l;
    int o = j - boff[l];
    float sc = a.g[l][o] / sqrtf(a.rv[l][o] + 1e-5f);
    bias[j] = a.be[l][o] - a.rm[l][o] * sc;
  }
}

// exact (non-contracted) squared distance, matching numpy op order
__device__ __forceinline__ float dist2_exact(float px, float py, float pz,
                                             float cx, float cy, float cz) {
  float dx = px - cx, dy = py - cy, dz = pz - cz;
  return __fadd_rn(__fadd_rn(__fmul_rn(dx, dx), __fmul_rn(dy, dy)), __fmul_rn(dz, dz));
}

__device__ __forceinline__ float wave_max64(float v) {
  #pragma unroll
  for (int off = 32; off >= 1; off >>= 1)
    v = fmaxf(v, __shfl_xor(v, (unsigned)off, 64));
  return v;
}

// ---------------- FPS stage 1 (+ fused weight prep): N=4096, npoint=128 ------
// blocks 0..63: FPS for batch b. blocks 64..562: prep.
// Contiguous point ownership: thread t owns points [16t, 16t+16).
__global__ __launch_bounds__(256) void fps1_prep_kernel(const float* __restrict__ pc,
    float* __restrict__ newxyz, PrepArgs pa, float* __restrict__ wT,
    float* __restrict__ bias) {
  int t = threadIdx.x;
  if (blockIdx.x >= 64) {
    prep_body(pa, wT, bias, (int)(blockIdx.x - 64) * 256 + t);
    return;
  }
  int b = blockIdx.x;
  const float* xb = pc + (size_t)b * 4096 * 3;
  float* out = newxyz + (size_t)b * 128 * 3;
  __shared__ float s_pts[4096 * 3];
  __shared__ float s_v[2][4];
  __shared__ int s_i[2][4];
  for (int e = t; e < 4096 * 3; e += 256) s_pts[e] = xb[e];
  __syncthreads();
  float px[16], py[16], pz[16], dist[16];
  #pragma unroll
  for (int k = 0; k < 16; ++k) {
    int i = t * 16 + k;
    px[k] = s_pts[i * 3]; py[k] = s_pts[i * 3 + 1]; pz[k] = s_pts[i * 3 + 2];
    dist[k] = 1e10f;
  }
  float cx = s_pts[0], cy = s_pts[1], cz = s_pts[2];
  if (t == 0) { out[0] = cx; out[1] = cy; out[2] = cz; }
  int lane = t & 63, wv = t >> 6, base = t * 16;
  for (int it = 1; it < 128; ++it) {
    float bv = -1.f; int lidx = base;
    #pragma unroll
    for (int k = 0; k < 16; ++k) {
      float d = dist2_exact(px[k], py[k], pz[k], cx, cy, cz);
      float nd = fminf(dist[k], d);
      dist[k] = nd;
      if (nd > bv) { bv = nd; lidx = base + k; }  // strict > keeps first (smallest k)
    }
    float wm = wave_max64(bv);
    unsigned long long m = __ballot(bv == wm);
    int src = __ffsll(m) - 1;            // smallest lane achieving wm -> smallest idx
    int widx = __shfl(lidx, src, 64);
    int pb = it & 1;
    if (lane == 0) { s_v[pb][wv] = wm; s_i[pb][wv] = widx; }
    __syncthreads();
    float v0 = s_v[pb][0]; int i0 = s_i[pb][0];
    #pragma unroll
    for (int w = 1; w < 4; ++w) {
      float v = s_v[pb][w]; int ii = s_i[pb][w];
      if (v > v0 || (v == v0 && ii < i0)) { v0 = v; i0 = ii; }
    }
    cx = s_pts[i0 * 3]; cy = s_pts[i0 * 3 + 1]; cz = s_pts[i0 * 3 + 2];
    if (t == 0) { out[it * 3] = cx; out[it * 3 + 1] = cy; out[it * 3 + 2] = cz; }
  }
}

// ---------------- FPS stage 2 body: N=128, npoint=64, one wave ----------------
// Contiguous ownership: lane t owns points {2t, 2t+1}.
__device__ __forceinline__ void fps2_body(const float* __restrict__ xyz1,
                                          float* __restrict__ out_xyz, int b, int t) {
  const float* xb = xyz1 + (size_t)b * 128 * 3;
  float* out = out_xyz + (size_t)b * 64 * 3;
  float px[2], py[2], pz[2], dist[2];
  #pragma unroll
  for (int k = 0; k < 2; ++k) {
    int i = t * 2 + k;
    px[k] = xb[i * 3]; py[k] = xb[i * 3 + 1]; pz[k] = xb[i * 3 + 2];
    dist[k] = 1e10f;
  }
  float cx = __shfl(px[0], 0, 64), cy = __shfl(py[0], 0, 64), cz = __shfl(pz[0], 0, 64);
  if (t == 0) { out[0] = cx; out[1] = cy; out[2] = cz; }
  for (int it = 1; it < 64; ++it) {
    float bv = -1.f; int lidx = t * 2;
    #pragma unroll
    for (int k = 0; k < 2; ++k) {
      float d = dist2_exact(px[k], py[k], pz[k], cx, cy, cz);
      float nd = fminf(dist[k], d);
      dist[k] = nd;
      if (nd > bv) { bv = nd; lidx = t * 2 + k; }
    }
    float wm = wave_max64(bv);
    unsigned long long m = __ballot(bv == wm);
    int src = __ffsll(m) - 1;
    int widx = __shfl(lidx, src, 64);
    int sl = widx >> 1, sk = widx & 1;  // both wave-uniform
    float qx = sk ? px[1] : px[0], qy = sk ? py[1] : py[0], qz = sk ? pz[1] : pz[0];
    cx = __shfl(qx, sl, 64); cy = __shfl(qy, sl, 64); cz = __shfl(qz, sl, 64);
    if (t == 0) { out[it * 3] = cx; out[it * 3 + 1] = cy; out[it * 3 + 2] = cz; }
  }
}

// ---------------- FPS stage 3 body: N=64, npoint=32, one wave ----------------
__device__ __forceinline__ void fps3_body(const float* __restrict__ xyz2,
                                          float* __restrict__ out_xyz, int b, int t) {
  const float* xb = xyz2 + (size_t)b * 64 * 3;
  float* out = out_xyz + (size_t)b * 32 * 3;
  float px = xb[t * 3], py = xb[t * 3 + 1], pz = xb[t * 3 + 2];
  float dist = 1e10f;
  float cx = __shfl(px, 0, 64), cy = __shfl(py, 0, 64), cz = __shfl(pz, 0, 64);
  if (t == 0) { out[0] = cx; out[1] = cy; out[2] = cz; }
  for (int it = 1; it < 32; ++it) {
    float d = dist2_exact(px, py, pz, cx, cy, cz);
    dist = fminf(dist, d);
    float wm = wave_max64(dist);
    unsigned long long m = __ballot(dist == wm);
    int widx = __ffsll(m) - 1;
    cx = __shfl(px, widx, 64); cy = __shfl(py, widx, 64); cz = __shfl(pz, widx, 64);
    if (t == 0) { out[it * 3] = cx; out[it * 3 + 1] = cy; out[it * 3 + 2] = cz; }
  }
}

// ---------------- ball query (single wave) ----------------
__device__ __forceinline__ int ball_query_wave(const float* __restrict__ xb, int N,
                                               float cx, float cy, float cz, float r2,
                                               int nsample, int* list, int lane) {
  int cnt = 0;
  for (int base = 0; base < N && cnt < nsample; base += 64) {
    int i = base + lane;
    float d2 = dist2_exact(xb[i * 3], xb[i * 3 + 1], xb[i * 3 + 2], cx, cy, cz);
    bool in = d2 < r2;
    unsigned long long m = __ballot(in);
    if (in) {
      int pos = cnt + __popcll(m & ((1ull << lane) - 1ull));
      if (pos < nsample) list[pos] = i;
    }
    cnt += __popcll(m);
  }
  return cnt;
}

#define FMA4(aq, w0, w1, w2, w3, xv, comp)                                   \
  aq = fmaf(w0.comp, xv.x, fmaf(w1.comp, xv.y, fmaf(w2.comp, xv.z,           \
       fmaf(w3.comp, xv.w, aq))))

// ---------------- group+MLP stage 1 (+ fused fps2): 8 groups/block -----------
// blockIdx.x < 16: group work (2 chunks of 128 j). blockIdx.x == 16: fps2.
__global__ __launch_bounds__(256) void group1_fps2_kernel(const float* __restrict__ pc,
    const float* __restrict__ newxyz1, const float* __restrict__ wbuf,
    const float* __restrict__ bbuf, float* __restrict__ f1,
    float* __restrict__ xyz2) {
  int t = threadIdx.x;
  int b = blockIdx.y;
  if (blockIdx.x == 16) {
    if (t < 64) fps2_body(newxyz1, xyz2, b, t);
    return;
  }
  __shared__ float W0s[384];       // [12][32]
  __shared__ float W1s[2048];      // [32][64]
  __shared__ float X[128 * 12];
  __shared__ float h1[128 * 36];   // stride 36
  __shared__ float pm1[16 * 64];
  __shared__ float ctr[24];
  __shared__ int lst[256];         // [8][32]
  __shared__ int cnts[8];
  int s0 = blockIdx.x * 8;
  const float* xb = pc + (size_t)b * 4096 * 3;
  for (int e = t; e < 384; e += 256) W0s[e] = wbuf[e];
  for (int e = t; e < 2048; e += 256) W1s[e] = wbuf[384 + e];
  int lane = t & 63, wv = t >> 6;
  for (int k = 0; k < 2; ++k) {
    int g = wv * 2 + k;
    const float* c3 = newxyz1 + ((size_t)b * 128 + s0 + g) * 3;
    float cx = c3[0], cy = c3[1], cz = c3[2];
    if (lane == 0) { ctr[g * 3] = cx; ctr[g * 3 + 1] = cy; ctr[g * 3 + 2] = cz; }
    int cnt = ball_query_wave(xb, 4096, cx, cy, cz, 4.0e-4f, 32, lst + g * 32, lane);
    if (lane == 0) cnts[g] = cnt;
  }
  __syncthreads();
  { int g = t >> 5, q = t & 31; if (q >= cnts[g]) lst[t] = (cnts[g] > 0) ? lst[g * 32] : 0; }
  __syncthreads();
  int o_l0 = t & 31, jb0 = (t >> 5) * 16;
  float w0v[12];
  #pragma unroll
  for (int c = 0; c < 12; ++c) w0v[c] = W0s[c * 32 + o_l0];
  float b0 = bbuf[o_l0];
  int ot1 = t & 15, jt1 = t >> 4;
  int o0 = ot1 * 4, j0 = jt1 * 8;
  float bias1[4];
  #pragma unroll
  for (int r = 0; r < 4; ++r) bias1[r] = bbuf[32 + o0 + r];
  for (int chunk = 0; chunk < 2; ++chunk) {
    if (t < 128) {
      int j = t;
      int g = chunk * 4 + (j >> 5);
      int i = lst[g * 32 + (j & 31)];
      float px = xb[i * 3], py = xb[i * 3 + 1], pz = xb[i * 3 + 2];
      float4 v0, v1, v2;
      v0.x = px - ctr[g * 3]; v0.y = py - ctr[g * 3 + 1]; v0.z = pz - ctr[g * 3 + 2];
      v0.w = px; v1.x = py; v1.y = pz; v1.z = px; v1.w = py;
      v2.x = pz; v2.y = 0.f; v2.z = 0.f; v2.w = 0.f;
      *reinterpret_cast<float4*>(&X[j * 12 + 0]) = v0;
      *reinterpret_cast<float4*>(&X[j * 12 + 4]) = v1;
      *reinterpret_cast<float4*>(&X[j * 12 + 8]) = v2;
    }
    __syncthreads();
    // layer0: o = t&31, 16 j per thread
    for (int jj = 0; jj < 16; ++jj) {
      int j = jb0 + jj;
      float4 x0 = *reinterpret_cast<const float4*>(&X[j * 12 + 0]);
      float4 x1 = *reinterpret_cast<const float4*>(&X[j * 12 + 4]);
      float4 x2 = *reinterpret_cast<const float4*>(&X[j * 12 + 8]);
      float a = b0;
      a = fmaf(w0v[0], x0.x, a); a = fmaf(w0v[1], x0.y, a);
      a = fmaf(w0v[2], x0.z, a); a = fmaf(w0v[3], x0.w, a);
      a = fmaf(w0v[4], x1.x, a); a = fmaf(w0v[5], x1.y, a);
      a = fmaf(w0v[6], x1.z, a); a = fmaf(w0v[7], x1.w, a);
      a = fmaf(w0v[8], x2.x, a); a = fmaf(w0v[9], x2.y, a);
      a = fmaf(w0v[10], x2.z, a); a = fmaf(w0v[11], x2.w, a);
      h1[j * 36 + o_l0] = fmaxf(a, 0.f);
    }
    __syncthreads();
    // layer1: tile 4o x 8j over [64 o][128 j], K=32
    float acc[8][4];
    #pragma unroll
    for (int q = 0; q < 8; ++q)
      #pragma unroll
      for (int r = 0; r < 4; ++r) acc[q][r] = bias1[r];
    for (int c4 = 0; c4 < 8; ++c4) {
      int c = c4 * 4;
      float4 w0 = *reinterpret_cast<const float4*>(&W1s[(c + 0) * 64 + o0]);
      float4 w1 = *reinterpret_cast<const float4*>(&W1s[(c + 1) * 64 + o0]);
      float4 w2 = *reinterpret_cast<const float4*>(&W1s[(c + 2) * 64 + o0]);
      float4 w3 = *reinterpret_cast<const float4*>(&W1s[(c + 3) * 64 + o0]);
      #pragma unroll
      for (int q = 0; q < 8; ++q) {
        float4 xv = *reinterpret_cast<const float4*>(&h1[(j0 + q) * 36 + c]);
        FMA4(acc[q][0], w0, w1, w2, w3, xv, x);
        FMA4(acc[q][1], w0, w1, w2, w3, xv, y);
        FMA4(acc[q][2], w0, w1, w2, w3, xv, z);
        FMA4(acc[q][3], w0, w1, w2, w3, xv, w);
      }
    }
    {
      float m[4] = {-1e30f, -1e30f, -1e30f, -1e30f};
      #pragma unroll
      for (int q = 0; q < 8; ++q)
        #pragma unroll
        for (int r = 0; r < 4; ++r) m[r] = fmaxf(m[r], acc[q][r]);
      float4 mv; mv.x = m[0]; mv.y = m[1]; mv.z = m[2]; mv.w = m[3];
      *reinterpret_cast<float4*>(&pm1[jt1 * 64 + o0]) = mv;
    }
    __syncthreads();
    {
      int o = t & 63, g = t >> 6;
      float v = pm1[(4 * g + 0) * 64 + o];
      v = fmaxf(v, pm1[(4 * g + 1) * 64 + o]);
      v = fmaxf(v, pm1[(4 * g + 2) * 64 + o]);
      v = fmaxf(v, pm1[(4 * g + 3) * 64 + o]);
      f1[((size_t)b * 128 + s0 + chunk * 4 + g) * 64 + o] = fmaxf(v, 0.f);
    }
    __syncthreads();
  }
}

// ---------------- group+MLP stage 2 (+ fused fps3): 8 groups/block -----------
// blockIdx.x < 8: group work (4 chunks of 64 j). blockIdx.x == 8: fps3.
__global__ __launch_bounds__(256) void group2_fps3_kernel(const float* __restrict__ xyz1,
    const float* __restrict__ newxyz2, const float* __restrict__ f1,
    const float* __restrict__ wbuf, const float* __restrict__ bbuf,
    float* __restrict__ f2, float* __restrict__ xyz3) {
  int t = threadIdx.x;
  int b = blockIdx.y;
  if (blockIdx.x == 8) {
    if (t < 64) fps3_body(newxyz2, xyz3, b, t);
    return;
  }
  __shared__ float Xs[64 * 68];
  __shared__ float Hs[64 * 132];
  __shared__ float pm[8 * 128];
  __shared__ float ctr[24];
  __shared__ int lst[256];  // [8][32]
  __shared__ int cnts[8];
  int s0 = blockIdx.x * 8;
  const float* xb = xyz1 + (size_t)b * 128 * 3;
  const float* W2g = wbuf + 2432;
  const float* W3g = wbuf + 11136;
  int lane = t & 63, wv = t >> 6;
  for (int k = 0; k < 2; ++k) {
    int g = wv * 2 + k;
    const float* c3 = newxyz2 + ((size_t)b * 64 + s0 + g) * 3;
    float cx = c3[0], cy = c3[1], cz = c3[2];
    if (lane == 0) { ctr[g * 3] = cx; ctr[g * 3 + 1] = cy; ctr[g * 3 + 2] = cz; }
    int cnt = ball_query_wave(xb, 128, cx, cy, cz, 1.6e-3f, 32, lst + g * 32, lane);
    if (lane == 0) cnts[g] = cnt;
  }
  __syncthreads();
  { int g = t >> 5, q = t & 31; if (q >= cnts[g]) lst[t] = (cnts[g] > 0) ? lst[g * 32] : 0; }
  __syncthreads();
  int ot = t & 31, jt = t >> 5;
  int o0 = ot * 4, j0 = jt * 8;
  float bias2[4], bias3[4];
  #pragma unroll
  for (int r = 0; r < 4; ++r) {
    bias2[r] = bbuf[96 + o0 + r];
    bias3[r] = bbuf[224 + o0 + r];
  }
  for (int chunk = 0; chunk < 4; ++chunk) {
    for (int e = t; e < 64 * 17; e += 256) {
      int j = e & 63, q = e >> 6;
      int g = chunk * 2 + (j >> 5);
      int i = lst[g * 32 + (j & 31)];
      const float* f1r = f1 + ((size_t)b * 128 + i) * 64;
      int c = q * 4;
      float vv[4];
      #pragma unroll
      for (int u = 0; u < 4; ++u) {
        int cc = c + u;
        float x;
        if (cc < 3) x = xb[i * 3 + cc] - ctr[g * 3 + cc];
        else if (cc < 67) x = f1r[cc - 3];
        else x = 0.f;
        vv[u] = x;
      }
      float4 v; v.x = vv[0]; v.y = vv[1]; v.z = vv[2]; v.w = vv[3];
      *reinterpret_cast<float4*>(&Xs[j * 68 + c]) = v;
    }
    __syncthreads();
    float acc[8][4];
    // layer2: [128 o x 64 j], K=68
    #pragma unroll
    for (int q = 0; q < 8; ++q)
      #pragma unroll
      for (int r = 0; r < 4; ++r) acc[q][r] = bias2[r];
    for (int c4 = 0; c4 < 17; ++c4) {
      int c = c4 * 4;
      float4 w0 = *reinterpret_cast<const float4*>(&W2g[(c + 0) * 128 + o0]);
      float4 w1 = *reinterpret_cast<const float4*>(&W2g[(c + 1) * 128 + o0]);
      float4 w2 = *reinterpret_cast<const float4*>(&W2g[(c + 2) * 128 + o0]);
      float4 w3 = *reinterpret_cast<const float4*>(&W2g[(c + 3) * 128 + o0]);
      #pragma unroll
      for (int q = 0; q < 8; ++q) {
        float4 xv = *reinterpret_cast<const float4*>(&Xs[(j0 + q) * 68 + c]);
        FMA4(acc[q][0], w0, w1, w2, w3, xv, x);
        FMA4(acc[q][1], w0, w1, w2, w3, xv, y);
        FMA4(acc[q][2], w0, w1, w2, w3, xv, z);
        FMA4(acc[q][3], w0, w1, w2, w3, xv, w);
      }
    }
    #pragma unroll
    for (int q = 0; q < 8; ++q) {
      float4 hv;
      hv.x = fmaxf(acc[q][0], 0.f); hv.y = fmaxf(acc[q][1], 0.f);
      hv.z = fmaxf(acc[q][2], 0.f); hv.w = fmaxf(acc[q][3], 0.f);
      *reinterpret_cast<float4*>(&Hs[(j0 + q) * 132 + o0]) = hv;
    }
    __syncthreads();
    // layer3: [128 o x 64 j], K=128
    #pragma unroll
    for (int q = 0; q < 8; ++q)
      #pragma unroll
      for (int r = 0; r < 4; ++r) acc[q][r] = bias3[r];
    for (int c4 = 0; c4 < 32; ++c4) {
      int c = c4 * 4;
      float4 w0 = *reinterpret_cast<const float4*>(&W3g[(c + 0) * 128 + o0]);
      float4 w1 = *reinterpret_cast<const float4*>(&W3g[(c + 1) * 128 + o0]);
      float4 w2 = *reinterpret_cast<const float4*>(&W3g[(c + 2) * 128 + o0]);
      float4 w3 = *reinterpret_cast<const float4*>(&W3g[(c + 3) * 128 + o0]);
      #pragma unroll
      for (int q = 0; q < 8; ++q) {
        float4 xv = *reinterpret_cast<const float4*>(&Hs[(j0 + q) * 132 + c]);
        FMA4(acc[q][0], w0, w1, w2, w3, xv, x);
        FMA4(acc[q][1], w0, w1, w2, w3, xv, y);
        FMA4(acc[q][2], w0, w1, w2, w3, xv, z);
        FMA4(acc[q][3], w0, w1, w2, w3, xv, w);
      }
    }
    {
      float m[4] = {-1e30f, -1e30f, -1e30f, -1e30f};
      #pragma unroll
      for (int q = 0; q < 8; ++q)
        #pragma unroll
        for (int r = 0; r < 4; ++r) m[r] = fmaxf(m[r], acc[q][r]);
      float4 mv; mv.x = m[0]; mv.y = m[1]; mv.z = m[2]; mv.w = m[3];
      *reinterpret_cast<float4*>(&pm[jt * 128 + o0]) = mv;
    }
    __syncthreads();
    {
      int o = t & 127, h = t >> 7;
      float v = pm[(4 * h + 0) * 128 + o];
      v = fmaxf(v, pm[(4 * h + 1) * 128 + o]);
      v = fmaxf(v, pm[(4 * h + 2) * 128 + o]);
      v = fmaxf(v, pm[(4 * h + 3) * 128 + o]);
      f2[((size_t)b * 64 + s0 + chunk * 2 + h) * 128 + o] = fmaxf(v, 0.f);
    }
    __syncthreads();
  }
}

// ---------------- group+MLP stage 3: 4 groups/block, 2 chunks of 32 j --------
__global__ __launch_bounds__(256) void group3_kernel(const float* __restrict__ xyz2,
    const float* __restrict__ newxyz3, const float* __restrict__ f2,
    const float* __restrict__ wbuf, const float* __restrict__ bbuf,
    float* __restrict__ out) {
  __shared__ float X3[32 * 132];
  __shared__ float Hs3[32 * 260];
  __shared__ float pm3[4 * 256];
  __shared__ float ctr[12];
  __shared__ int lst[64];  // [4][16]
  __shared__ int cnts[4];
  int t = threadIdx.x;
  int b = blockIdx.y, s0 = blockIdx.x * 4;
  const float* xb = xyz2 + (size_t)b * 64 * 3;
  const float* W4g = wbuf + 27520;
  const float* W5g = wbuf + 61312;
  int lane = t & 63, wv = t >> 6;
  {
    int g = wv;
    const float* c3 = newxyz3 + ((size_t)b * 32 + s0 + g) * 3;
    float cx = c3[0], cy = c3[1], cz = c3[2];
    if (lane == 0) { ctr[g * 3] = cx; ctr[g * 3 + 1] = cy; ctr[g * 3 + 2] = cz; }
    int cnt = ball_query_wave(xb, 64, cx, cy, cz, 6.4e-3f, 16, lst + g * 16, lane);
    if (lane == 0) cnts[g] = cnt;
  }
  __syncthreads();
  if (t < 64) { int g = t >> 4, q = t & 15; if (q >= cnts[g]) lst[t] = (cnts[g] > 0) ? lst[g * 16] : 0; }
  __syncthreads();
  int ot = t & 63, jt = t >> 6;
  int o0 = ot * 4, j0 = jt * 8;
  float bias4[4], bias5[4];
  #pragma unroll
  for (int r = 0; r < 4; ++r) {
    bias4[r] = bbuf[352 + o0 + r];
    bias5[r] = bbuf[608 + o0 + r];
  }
  for (int chunk = 0; chunk < 2; ++chunk) {
    for (int e = t; e < 32 * 33; e += 256) {
      int j = e & 31, q = e >> 5;  // q 0..32
      int g = chunk * 2 + (j >> 4);
      int i = lst[g * 16 + (j & 15)];
      const float* f2r = f2 + ((size_t)b * 64 + i) * 128;
      int c = q * 4;
      float vv[4];
      #pragma unroll
      for (int u = 0; u < 4; ++u) {
        int cc = c + u;
        float x;
        if (cc < 3) x = xb[i * 3 + cc] - ctr[g * 3 + cc];
        else if (cc < 131) x = f2r[cc - 3];
        else x = 0.f;
        vv[u] = x;
      }
      float4 v; v.x = vv[0]; v.y = vv[1]; v.z = vv[2]; v.w = vv[3];
      *reinterpret_cast<float4*>(&X3[j * 132 + c]) = v;
    }
    __syncthreads();
    float acc[8][4];
    // layer4: [256 o x 32 j], K=132
    #pragma unroll
    for (int q = 0; q < 8; ++q)
      #pragma unroll
      for (int r = 0; r < 4; ++r) acc[q][r] = bias4[r];
    for (int c4 = 0; c4 < 33; ++c4) {
      int c = c4 * 4;
      float4 w0 = *reinterpret_cast<const float4*>(&W4g[(c + 0) * 256 + o0]);
      float4 w1 = *reinterpret_cast<const float4*>(&W4g[(c + 1) * 256 + o0]);
      float4 w2 = *reinterpret_cast<const float4*>(&W4g[(c + 2) * 256 + o0]);
      float4 w3 = *reinterpret_cast<const float4*>(&W4g[(c + 3) * 256 + o0]);
      #pragma unroll
      for (int q = 0; q < 8; ++q) {
        float4 xv = *reinterpret_cast<const float4*>(&X3[(j0 + q) * 132 + c]);
        FMA4(acc[q][0], w0, w1, w2, w3, xv, x);
        FMA4(acc[q][1], w0, w1, w2, w3, xv, y);
        FMA4(acc[q][2], w0, w1, w2, w3, xv, z);
        FMA4(acc[q][3], w0, w1, w2, w3, xv, w);
      }
    }
    #pragma unroll
    for (int q = 0; q < 8; ++q) {
      float4 hv;
      hv.x = fmaxf(acc[q][0], 0.f); hv.y = fmaxf(acc[q][1], 0.f);
      hv.z = fmaxf(acc[q][2], 0.f); hv.w = fmaxf(acc[q][3], 0.f);
      *reinterpret_cast<float4*>(&Hs3[(j0 + q) * 260 + o0]) = hv;
    }
    __syncthreads();
    // layer5: [256 o x 32 j], K=256
    #pragma unroll
    for (int q = 0; q < 8; ++q)
      #pragma unroll
      for (int r = 0; r < 4; ++r) acc[q][r] = bias5[r];
    for (int c4 = 0; c4 < 64; ++c4) {
      int c = c4 * 4;
      float4 w0 = *reinterpret_cast<const float4*>(&W5g[(c + 0) * 256 + o0]);
      float4 w1 = *reinterpret_cast<const float4*>(&W5g[(c + 1) * 256 + o0]);
      float4 w2 = *reinterpret_cast<const float4*>(&W5g[(c + 2) * 256 + o0]);
      float4 w3 = *reinterpret_cast<const float4*>(&W5g[(c + 3) * 256 + o0]);
      #pragma unroll
      for (int q = 0; q < 8; ++q) {
        float4 xv = *reinterpret_cast<const float4*>(&Hs3[(j0 + q) * 260 + c]);
        FMA4(acc[q][0], w0, w1, w2, w3, xv, x);
        FMA4(acc[q][1], w0, w1, w2, w3, xv, y);
        FMA4(acc[q][2], w0, w1, w2, w3, xv, z);
        FMA4(acc[q][3], w0, w1, w2, w3, xv, w);
      }
    }
    {
      float m[4] = {-1e30f, -1e30f, -1e30f, -1e30f};
      #pragma unroll
      for (int q = 0; q < 8; ++q)
        #pragma unroll
        for (int r = 0; r < 4; ++r) m[r] = fmaxf(m[r], acc[q][r]);
      float4 mv; mv.x = m[0]; mv.y = m[1]; mv.z = m[2]; mv.w = m[3];
      *reinterpret_cast<float4*>(&pm3[jt * 256 + o0]) = mv;
    }
    __syncthreads();
    {
      int o = t;
      #pragma unroll
      for (int g = 0; g < 2; ++g) {
        float v = fmaxf(pm3[(2 * g) * 256 + o], pm3[(2 * g + 1) * 256 + o]);
        out[((size_t)b * 256 + o) * 32 + s0 + chunk * 2 + g] = fmaxf(v, 0.f);
      }
    }
    __syncthreads();
  }
}

extern "C" void kernel_launch(void* const* d_in, const int* in_sizes, int n_in,
                              void* d_out, int out_size, void* d_ws, size_t ws_size,
                              hipStream_t stream) {
  (void)in_sizes; (void)n_in; (void)out_size; (void)ws_size;
  const float* pc = (const float*)d_in[0];
  PrepArgs pa;
  for (int l = 0; l < 6; ++l) {
    pa.w[l]  = (const float*)d_in[1 + 5 * l + 0];
    pa.g[l]  = (const float*)d_in[1 + 5 * l + 1];
    pa.be[l] = (const float*)d_in[1 + 5 * l + 2];
    pa.rm[l] = (const float*)d_in[1 + 5 * l + 3];
    pa.rv[l] = (const float*)d_in[1 + 5 * l + 4];
  }
  float* ws = (float*)d_ws;
  float* wbuf = ws + 0;
  float* bbuf = ws + 126848;
  float* xyz1 = ws + 131072;
  float* xyz2 = ws + 155648;
  float* xyz3 = ws + 167936;
  float* f1   = ws + 174080;
  float* f2   = ws + 698368;
  float* out  = (float*)d_out;

  fps1_prep_kernel<<<563, 256, 0, stream>>>(pc, xyz1, pa, wbuf, bbuf);
  group1_fps2_kernel<<<dim3(17, 64), 256, 0, stream>>>(pc, xyz1, wbuf, bbuf, f1, xyz2);
  group2_fps3_kernel<<<dim3(9, 64), 256, 0, stream>>>(xyz1, xyz2, f1, wbuf, bbuf, f2, xyz3);
  group3_kernel<<<dim3(8, 64), 256, 0, stream>>>(xyz2, xyz3, f2, wbuf, bbuf, out);
}